// Round 1
// baseline (187.395 us; speedup 1.0000x reference)
//
#include <hip/hip_runtime.h>
#include <hip/hip_bf16.h>

// out[r] = sum_i cos(x[r][i]) * w[i] + b   (theta unused; RZ leaves <Z> invariant)
// B = 1048576 rows, W = 32 cols. Pure streaming kernel, memory-bound.
//
// Mapping: 8 lanes per row, each lane loads one float4 (16B). Global float4
// index == global thread id -> perfectly coalesced. Width-8 shuffle reduce.

#define BATCH 1048576
#define WIRES 32

__global__ __launch_bounds__(256) void hybrid_regression_kernel(
    const float4* __restrict__ x4,   // BATCH*8 float4s
    const float*  __restrict__ w,    // 32 floats
    const float*  __restrict__ bias, // 1 float
    float*        __restrict__ out)  // BATCH floats
{
    const int tid = blockIdx.x * 256 + threadIdx.x;   // 0 .. BATCH*8-1
    const int seg = threadIdx.x & 7;                  // which quarter-of-row

    const float4 v  = x4[tid];
    const float4 wv = ((const float4*)w)[seg];

    float p = __cosf(v.x) * wv.x
            + __cosf(v.y) * wv.y
            + __cosf(v.z) * wv.z
            + __cosf(v.w) * wv.w;

    // reduce across the 8 lanes covering this row
    p += __shfl_down(p, 4, 8);
    p += __shfl_down(p, 2, 8);
    p += __shfl_down(p, 1, 8);

    if (seg == 0) {
        out[tid >> 3] = p + bias[0];
    }
}

extern "C" void kernel_launch(void* const* d_in, const int* in_sizes, int n_in,
                              void* d_out, int out_size, void* d_ws, size_t ws_size,
                              hipStream_t stream) {
    const float* x    = (const float*)d_in[0];
    // d_in[1] = theta, unused (RZ phase does not affect <Z>)
    const float* w    = (const float*)d_in[2];
    const float* bias = (const float*)d_in[3];
    float* out        = (float*)d_out;

    const int total_threads = BATCH * (WIRES / 4);    // 8,388,608
    const int block = 256;
    const int grid  = total_threads / block;          // 32,768

    hybrid_regression_kernel<<<grid, block, 0, stream>>>(
        (const float4*)x, w, bias, out);
}